// Round 6
// baseline (381.798 us; speedup 1.0000x reference)
//
#include <hip/hip_runtime.h>
#include <hip/hip_bf16.h>
#include <math.h>

#define BATCH 4

typedef __bf16 bf16x8 __attribute__((ext_vector_type(8)));
typedef float f32x4 __attribute__((ext_vector_type(4)));

#define LDSTRIDE 40  // bf16 units per LDS row (80 B): conflict-free b128 access

// ---------------- K1: convert teacher rows to bf16 (extra rows pre-normalized) ----------------
__global__ __launch_bounds__(256) void convert_kernel(const float* __restrict__ teacher,
                                                      const int* __restrict__ ref_perm,
                                                      __bf16* __restrict__ Abf,
                                                      __bf16* __restrict__ Bbf,
                                                      float* __restrict__ invnorm,
                                                      float* __restrict__ acc) {
    int blk = blockIdx.x;            // b*4352 + r
    int b = blk / 4352;
    int r = blk - b * 4352;
    int t = threadIdx.x;
    if (blk == 0 && t < 4) acc[t] = 0.f;   // replaces memset dispatch
    const float* src;
    __bf16* dst;
    bool isB = (r >= 256);
    if (!isB) {
        src = teacher + (((size_t)b * 8 + 0) * 1024 + ref_perm[r]) * 1024;
        dst = Abf + ((size_t)b * 256 + r) * 1024;
    } else {
        int m = r - 256;
        int frame = 1 + 2 * (m >> 10), p = m & 1023;
        src = teacher + (((size_t)b * 8 + frame) * 1024 + p) * 1024;
        dst = Bbf + ((size_t)b * 4096 + m) * 1024;
    }
    float4 v = ((const float4*)src)[t];
    float scale = 1.0f;
    __shared__ float red[4];
    if (isB) {
        float s = v.x * v.x + v.y * v.y + v.z * v.z + v.w * v.w;
        for (int o = 32; o > 0; o >>= 1) s += __shfl_xor(s, o);
        if ((t & 63) == 0) red[t >> 6] = s;
        __syncthreads();
        float tot = red[0] + red[1] + red[2] + red[3];
        scale = 1.0f / fmaxf(sqrtf(tot), 1e-12f);
        if (t == 0) invnorm[b * 4096 + (r - 256)] = scale;
    }
    __bf16 o4[4] = {(__bf16)(v.x * scale), (__bf16)(v.y * scale),
                    (__bf16)(v.z * scale), (__bf16)(v.w * scale)};
    ((uint2*)dst)[t] = *(uint2*)o4;
}

// ---------------- K2: bf16 MFMA GEMM, 4 waves/block (R2-proven shape) ----------------
__global__ __launch_bounds__(256) void mfma_gemm_kernel(const __bf16* __restrict__ Abf,
                                                        const __bf16* __restrict__ Bbf,
                                                        __bf16* __restrict__ scoresb) {
    int mt = blockIdx.x;    // 0..31
    int nt = blockIdx.y;    // 0..1
    int b  = blockIdx.z;    // 0..3
    int t = threadIdx.x;
    int lane = t & 63, wave = t >> 6;
    int wn0 = (wave & 1) * 64;
    int wm0 = (wave >> 1) * 64;
    int l15 = lane & 15, l4 = lane >> 4;

    __shared__ __bf16 As[128 * LDSTRIDE];
    __shared__ __bf16 Bs[128 * LDSTRIDE];

    const __bf16* Ab = Abf + ((size_t)b * 256 + nt * 128) * 1024;
    const __bf16* Bb = Bbf + ((size_t)b * 4096 + mt * 128) * 1024;

    int e0 = t, e1 = t + 256;
    int row0 = e0 >> 2, kc0 = e0 & 3;
    int row1 = e1 >> 2, kc1 = e1 & 3;

    f32x4 acc[4][4] = {};

    for (int k0 = 0; k0 < 1024; k0 += 32) {
        uint4 a0 = *(const uint4*)(Ab + (size_t)row0 * 1024 + k0 + kc0 * 8);
        uint4 a1 = *(const uint4*)(Ab + (size_t)row1 * 1024 + k0 + kc1 * 8);
        uint4 b0 = *(const uint4*)(Bb + (size_t)row0 * 1024 + k0 + kc0 * 8);
        uint4 b1 = *(const uint4*)(Bb + (size_t)row1 * 1024 + k0 + kc1 * 8);
        __syncthreads();   // prev iter's frag reads complete
        *(uint4*)(As + row0 * LDSTRIDE + kc0 * 8) = a0;
        *(uint4*)(As + row1 * LDSTRIDE + kc1 * 8) = a1;
        *(uint4*)(Bs + row0 * LDSTRIDE + kc0 * 8) = b0;
        *(uint4*)(Bs + row1 * LDSTRIDE + kc1 * 8) = b1;
        __syncthreads();
        bf16x8 af[4], bfr[4];
#pragma unroll
        for (int i = 0; i < 4; i++) {
            af[i]  = *(const bf16x8*)(As + (wn0 + i * 16 + l15) * LDSTRIDE + l4 * 8);
            bfr[i] = *(const bf16x8*)(Bs + (wm0 + i * 16 + l15) * LDSTRIDE + l4 * 8);
        }
#pragma unroll
        for (int i = 0; i < 4; i++)
#pragma unroll
            for (int j = 0; j < 4; j++)
                acc[i][j] = __builtin_amdgcn_mfma_f32_16x16x32_bf16(af[i], bfr[j], acc[i][j], 0, 0, 0);
    }

    __bf16* outp = scoresb + ((size_t)b * 256 + nt * 128) * 4096 + (size_t)mt * 128;
#pragma unroll
    for (int i = 0; i < 4; i++)
#pragma unroll
        for (int j = 0; j < 4; j++)
#pragma unroll
            for (int r = 0; r < 4; r++) {
                int n = wn0 + i * 16 + l4 * 4 + r;
                int m = wm0 + j * 16 + l15;
                outp[(size_t)n * 4096 + m] = (__bf16)acc[i][j][r];
            }
}

// ---------------- K3: top-8 -> exact rescore -> top-4 -> d2 branch (weight 3) ----------------
__global__ __launch_bounds__(256) void topk_d2_kernel(const __bf16* __restrict__ scoresb,
                                                      const float* __restrict__ teacher,
                                                      const float* __restrict__ student,
                                                      const int* __restrict__ ref_perm,
                                                      const float* __restrict__ invnorm,
                                                      int* __restrict__ topk,
                                                      float* __restrict__ acc) {
    int row = blockIdx.x;  // b*256+n
    int b = row >> 8, n = row & 255;
    int t = threadIdx.x;
    int lane = t & 63, wave = t >> 6;

    __shared__ float refr[1024], refs[1024];
    __shared__ float cval[32];
    __shared__ int cidx[32];
    __shared__ int cand_i[8];
    __shared__ float exact_v[8];
    __shared__ int wm4[4];

    const float* Tb = teacher + (size_t)b * 8 * 1024 * 1024;
    const float* Sb = student + (size_t)b * 4 * 1024 * 1024;
    int rp = ref_perm[n];
    ((float4*)refr)[t] = ((const float4*)(Tb + (size_t)rp * 1024))[t];
    ((float4*)refs)[t] = ((const float4*)(Sb + (size_t)rp * 1024))[t];

    // coalesced score load: thread t owns m in [16t, 16t+16)
    const __bf16* srow = scoresb + (size_t)row * 4096;
    __bf16 xs[16];
    *(uint4*)xs = ((const uint4*)srow)[2 * t];
    *(uint4*)(xs + 8) = ((const uint4*)srow)[2 * t + 1];

    float v[8]; int ix[8];
#pragma unroll
    for (int i = 0; i < 8; i++) { v[i] = -1e38f; ix[i] = -1; }
#pragma unroll
    for (int jj = 0; jj < 16; jj++) {
        float xv = (float)xs[jj]; int xm = t * 16 + jj;
        if (xv > v[7]) {
            v[7] = xv; ix[7] = xm;
#pragma unroll
            for (int i = 7; i > 0; i--)
                if (v[i] > v[i - 1]) {
                    float tv = v[i]; v[i] = v[i - 1]; v[i - 1] = tv;
                    int ti = ix[i]; ix[i] = ix[i - 1]; ix[i - 1] = ti;
                }
        }
    }
    // wave-level top-8: butterfly argmax on heads + static pop
    for (int r = 0; r < 8; r++) {
        float bv = v[0]; int bi = ix[0];
        for (int o = 32; o > 0; o >>= 1) {
            float ov = __shfl_xor(bv, o); int oi = __shfl_xor(bi, o);
            if (ov > bv || (ov == bv && oi > bi)) { bv = ov; bi = oi; }
        }
        if (lane == 0) { cval[wave * 8 + r] = bv; cidx[wave * 8 + r] = bi; }
        if (bi == ix[0]) {
            v[0] = v[1]; ix[0] = ix[1];
            v[1] = v[2]; ix[1] = ix[2];
            v[2] = v[3]; ix[2] = ix[3];
            v[3] = v[4]; ix[3] = ix[4];
            v[4] = v[5]; ix[4] = ix[5];
            v[5] = v[6]; ix[5] = ix[6];
            v[6] = v[7]; ix[6] = ix[7];
            v[7] = -1e38f; ix[7] = -1;
        }
    }
    __syncthreads();
    if (wave == 0) {   // block merge: 32 candidates -> top-8
        float mv = (lane < 32) ? cval[lane] : -1e38f;
        int mi = (lane < 32) ? cidx[lane] : -1;
        for (int r = 0; r < 8; r++) {
            float bv = mv; int bi = mi;
            for (int o = 32; o > 0; o >>= 1) {
                float ov = __shfl_xor(bv, o); int oi = __shfl_xor(bi, o);
                if (ov > bv || (ov == bv && oi > bi)) { bv = ov; bi = oi; }
            }
            if (lane == 0) cand_i[r] = bi;
            if (bi == mi) mv = -1e38f;
        }
    }
    __syncthreads();
    // exact fp32 rescore straight from global (rows are L2/L3 hot)
    for (int c = wave; c < 8; c += 4) {
        int m = cand_i[c];
        int frame = 1 + 2 * (m >> 10), p = m & 1023;
        const float* ext = Tb + ((size_t)frame * 1024 + p) * 1024;
        float s = 0.f;
#pragma unroll
        for (int jj = 0; jj < 16; jj++) {
            int d = lane + 64 * jj;
            s = fmaf(refr[d], ext[d], s);
        }
        for (int o = 32; o > 0; o >>= 1) s += __shfl_xor(s, o);
        if (lane == 0) exact_v[c] = s * invnorm[b * 4096 + m];
    }
    __syncthreads();
    if (t == 0) {
        unsigned used = 0;
        for (int r = 0; r < 4; r++) {
            float bv = -1e38f; int bc = 0;
            for (int c = 0; c < 8; c++)
                if (!(used & (1u << c)) && exact_v[c] > bv) { bv = exact_v[c]; bc = c; }
            used |= 1u << bc;
            wm4[r] = cand_i[bc];
            topk[row * 4 + r] = cand_i[bc];
        }
    }
    __syncthreads();
    // ---- d2 branch: KL(softmax(rt - sh_r) || softmax(rs - sh_r)), weight 3, wave r handles row r
    {
        int m = wm4[wave];
        int frame = 1 + 2 * (m >> 10), p = m & 1023;
        const float* shr = Tb + ((size_t)frame * 1024 + p) * 1024;  // L2-hot from rescore
        float dt[16], ds[16];
        float mt = -1e38f, ms = -1e38f;
#pragma unroll
        for (int j = 0; j < 16; j++) {
            int d = lane + 64 * j;
            float sv = shr[d];
            dt[j] = refr[d] - sv;
            ds[j] = refs[d] - sv;
            mt = fmaxf(mt, dt[j]);
            ms = fmaxf(ms, ds[j]);
        }
        for (int o = 32; o > 0; o >>= 1) {
            mt = fmaxf(mt, __shfl_xor(mt, o));
            ms = fmaxf(ms, __shfl_xor(ms, o));
        }
        float Zt = 0.f, Zs = 0.f, Tn = 0.f;
#pragma unroll
        for (int j = 0; j < 16; j++) {
            float et = __expf(dt[j] - mt);
            Zt += et;
            Zs += __expf(ds[j] - ms);
            Tn += et * (dt[j] - ds[j]);
        }
        for (int o = 32; o > 0; o >>= 1) {
            Zt += __shfl_xor(Zt, o);
            Zs += __shfl_xor(Zs, o);
            Tn += __shfl_xor(Tn, o);
        }
        if (lane == 0) {
            float kl = Tn / Zt - mt - __logf(Zt) + ms + __logf(Zs);
            float ax = fabsf(kl);
            float h = ax < 0.5f ? ax * ax : ax - 0.25f;
            atomicAdd(&acc[1], h * 3.0f);
        }
    }
}

// ---------------- K4: KL d1+d3 — int-offset LDS, ti split across blocks ----------------
// buf layout (floats): RT@0, RS@1024, ST@2048, SS@3072, SH4@4096..8191
#define RT 0
#define RS 1024
#define ST 2048
#define SS 3072
#define SH 4096
__global__ __launch_bounds__(256) void kl_kernel(const float* __restrict__ teacher,
                                                 const float* __restrict__ student,
                                                 const int* __restrict__ ref_perm,
                                                 const int* __restrict__ shared_perm,
                                                 const int* __restrict__ topk,
                                                 float* __restrict__ acc) {
    int row = blockIdx.x;        // b*256 + n
    int ti  = blockIdx.y;        // 0..2
    int b = row >> 8;
    int n = row & 255;
    int t = threadIdx.x;
    int lane = t & 63, wave = t >> 6;

    __shared__ float buf[8192];
    __shared__ float res2[2];    // [0]=d1, [1]=d3
    if (t < 2) res2[t] = 0.f;

    const float* Tb = teacher + (size_t)b * 8 * 1024 * 1024;
    const float* Sb = student + (size_t)b * 4 * 1024 * 1024;

    int rp = ref_perm[n];
    int sp = shared_perm[n];
    int t_idx = 2 * ti + 2;
    int s_idx = ti + 1;
    ((float4*)(buf + RT))[t] = ((const float4*)(Tb + (size_t)rp * 1024))[t];
    ((float4*)(buf + RS))[t] = ((const float4*)(Sb + (size_t)rp * 1024))[t];
    ((float4*)(buf + ST))[t] = ((const float4*)(Tb + ((size_t)t_idx * 1024 + sp) * 1024))[t];
    ((float4*)(buf + SS))[t] = ((const float4*)(Sb + ((size_t)s_idx * 1024 + sp) * 1024))[t];
#pragma unroll
    for (int k = 0; k < 4; k++) {
        int idx = topk[row * 4 + k];
        int frame = 1 + 2 * (idx >> 10), p = idx & 1023;
        ((float4*)(buf + SH + k * 1024))[t] = ((const float4*)(Tb + ((size_t)frame * 1024 + p) * 1024))[t];
    }
    __syncthreads();

    // rows: 0 = d1 (rt-st | rs-ss), 1..4 = d3 (st-sh | ss-sh)
    for (int r = wave; r < 5; r += 4) {
        int at, bt, as, bs, branch;
        if (r == 0) { at = RT; bt = ST;                 as = RS; bs = SS; branch = 0; }
        else        { at = ST; bt = SH + (r - 1) * 1024; as = SS; bs = bt; branch = 1; }

        float dt[16], ds[16];
        float mt = -1e38f, ms = -1e38f;
#pragma unroll
        for (int j = 0; j < 16; j++) {
            int d = lane + 64 * j;
            float av = buf[at + d], bv = buf[bt + d];
            float asv = buf[as + d], bsv = buf[bs + d];
            dt[j] = av - bv;
            ds[j] = asv - bsv;
            mt = fmaxf(mt, dt[j]);
            ms = fmaxf(ms, ds[j]);
        }
        for (int o = 32; o > 0; o >>= 1) {
            mt = fmaxf(mt, __shfl_xor(mt, o));
            ms = fmaxf(ms, __shfl_xor(ms, o));
        }
        float Zt = 0.f, Zs = 0.f, Tn = 0.f;
#pragma unroll
        for (int j = 0; j < 16; j++) {
            float et = __expf(dt[j] - mt);
            Zt += et;
            Zs += __expf(ds[j] - ms);
            Tn += et * (dt[j] - ds[j]);
        }
        for (int o = 32; o > 0; o >>= 1) {
            Zt += __shfl_xor(Zt, o);
            Zs += __shfl_xor(Zs, o);
            Tn += __shfl_xor(Tn, o);
        }
        if (lane == 0) {
            float kl = Tn / Zt - mt - __logf(Zt) + ms + __logf(Zs);
            float ax = fabsf(kl);
            float h = ax < 0.5f ? ax * ax : ax - 0.25f;
            atomicAdd(&res2[branch], h);
        }
    }
    __syncthreads();
    if (t == 0) atomicAdd(&acc[0], res2[0]);
    if (t == 1) atomicAdd(&acc[2], res2[1]);
}

// ---------------- K5: finalize ----------------
__global__ void finalize_kernel(const float* __restrict__ acc, float* __restrict__ out) {
    out[0] = acc[0] / 3072.f + acc[1] / 12288.f + acc[2] / 12288.f;
}

extern "C" void kernel_launch(void* const* d_in, const int* in_sizes, int n_in,
                              void* d_out, int out_size, void* d_ws, size_t ws_size,
                              hipStream_t stream) {
    const float* teacher = (const float*)d_in[0];
    const float* student = (const float*)d_in[1];
    const int* ref_perm = (const int*)d_in[2];
    const int* shared_perm = (const int*)d_in[3];
    float* out = (float*)d_out;

    char* ws = (char*)d_ws;
    float* acc     = (float*)ws;                         // 64 B
    float* invnorm = (float*)(ws + 64);                  // 16384 floats
    int*   topk    = (int*)(ws + 64 + 65536);            // 4096 ints
    __bf16* Abf    = (__bf16*)(ws + 64 + 65536 + 16384); // 4*256*1024
    __bf16* Bbf    = Abf + (size_t)4 * 256 * 1024;       // 4*4096*1024
    __bf16* scoresb = Bbf + (size_t)4 * 4096 * 1024;     // 4*256*4096

    convert_kernel<<<BATCH * 4352, 256, 0, stream>>>(teacher, ref_perm, Abf, Bbf, invnorm, acc);
    mfma_gemm_kernel<<<dim3(32, 2, 4), 256, 0, stream>>>(Abf, Bbf, scoresb);
    topk_d2_kernel<<<1024, 256, 0, stream>>>(scoresb, teacher, student, ref_perm, invnorm, topk, acc);
    kl_kernel<<<dim3(1024, 3), 256, 0, stream>>>(teacher, student, ref_perm, shared_perm, topk, acc);
    finalize_kernel<<<1, 1, 0, stream>>>(acc, out);
}

// Round 7
// 276.843 us; speedup vs baseline: 1.3791x; 1.3791x over previous
//
#include <hip/hip_runtime.h>
#include <hip/hip_bf16.h>
#include <math.h>

#define BATCH 4

typedef __bf16 bf16x8 __attribute__((ext_vector_type(8)));
typedef float f32x4 __attribute__((ext_vector_type(4)));

#define LDSTRIDE 40  // bf16 units per LDS row (80 B): conflict-free b128 access

// ---------------- K1: convert teacher rows to bf16 (extra rows pre-normalized) ----------------
__global__ __launch_bounds__(256) void convert_kernel(const float* __restrict__ teacher,
                                                      const int* __restrict__ ref_perm,
                                                      __bf16* __restrict__ Abf,
                                                      __bf16* __restrict__ Bbf,
                                                      float* __restrict__ invnorm,
                                                      float* __restrict__ acc) {
    int blk = blockIdx.x;            // b*4352 + r
    int b = blk / 4352;
    int r = blk - b * 4352;
    int t = threadIdx.x;
    if (blk == 0 && t < 4) acc[t] = 0.f;   // replaces memset dispatch
    const float* src;
    __bf16* dst;
    bool isB = (r >= 256);
    if (!isB) {
        src = teacher + (((size_t)b * 8 + 0) * 1024 + ref_perm[r]) * 1024;
        dst = Abf + ((size_t)b * 256 + r) * 1024;
    } else {
        int m = r - 256;
        int frame = 1 + 2 * (m >> 10), p = m & 1023;
        src = teacher + (((size_t)b * 8 + frame) * 1024 + p) * 1024;
        dst = Bbf + ((size_t)b * 4096 + m) * 1024;
    }
    float4 v = ((const float4*)src)[t];
    float scale = 1.0f;
    __shared__ float red[4];
    if (isB) {
        float s = v.x * v.x + v.y * v.y + v.z * v.z + v.w * v.w;
        for (int o = 32; o > 0; o >>= 1) s += __shfl_xor(s, o);
        if ((t & 63) == 0) red[t >> 6] = s;
        __syncthreads();
        float tot = red[0] + red[1] + red[2] + red[3];
        scale = 1.0f / fmaxf(sqrtf(tot), 1e-12f);
        if (t == 0) invnorm[b * 4096 + (r - 256)] = scale;
    }
    __bf16 o4[4] = {(__bf16)(v.x * scale), (__bf16)(v.y * scale),
                    (__bf16)(v.z * scale), (__bf16)(v.w * scale)};
    ((uint2*)dst)[t] = *(uint2*)o4;
}

// ---------------- K2: bf16 MFMA GEMM (exact R2/282-build shape: 4 waves, 64x64/wave) ----------------
__global__ __launch_bounds__(256) void mfma_gemm_kernel(const __bf16* __restrict__ Abf,
                                                        const __bf16* __restrict__ Bbf,
                                                        __bf16* __restrict__ scoresb) {
    int mt = blockIdx.x;    // 0..31
    int nt = blockIdx.y;    // 0..1
    int b  = blockIdx.z;    // 0..3
    int t = threadIdx.x;
    int lane = t & 63, wave = t >> 6;
    int wn0 = (wave & 1) * 64;
    int wm0 = (wave >> 1) * 64;
    int l15 = lane & 15, l4 = lane >> 4;

    __shared__ __bf16 As[128 * LDSTRIDE];
    __shared__ __bf16 Bs[128 * LDSTRIDE];

    const __bf16* Ab = Abf + ((size_t)b * 256 + nt * 128) * 1024;
    const __bf16* Bb = Bbf + ((size_t)b * 4096 + mt * 128) * 1024;

    int e0 = t, e1 = t + 256;
    int row0 = e0 >> 2, kc0 = e0 & 3;
    int row1 = e1 >> 2, kc1 = e1 & 3;

    f32x4 acc[4][4] = {};

    for (int k0 = 0; k0 < 1024; k0 += 32) {
        uint4 a0 = *(const uint4*)(Ab + (size_t)row0 * 1024 + k0 + kc0 * 8);
        uint4 a1 = *(const uint4*)(Ab + (size_t)row1 * 1024 + k0 + kc1 * 8);
        uint4 b0 = *(const uint4*)(Bb + (size_t)row0 * 1024 + k0 + kc0 * 8);
        uint4 b1 = *(const uint4*)(Bb + (size_t)row1 * 1024 + k0 + kc1 * 8);
        __syncthreads();   // prev iter's frag reads complete
        *(uint4*)(As + row0 * LDSTRIDE + kc0 * 8) = a0;
        *(uint4*)(As + row1 * LDSTRIDE + kc1 * 8) = a1;
        *(uint4*)(Bs + row0 * LDSTRIDE + kc0 * 8) = b0;
        *(uint4*)(Bs + row1 * LDSTRIDE + kc1 * 8) = b1;
        __syncthreads();
        bf16x8 af[4], bfr[4];
#pragma unroll
        for (int i = 0; i < 4; i++) {
            af[i]  = *(const bf16x8*)(As + (wn0 + i * 16 + l15) * LDSTRIDE + l4 * 8);
            bfr[i] = *(const bf16x8*)(Bs + (wm0 + i * 16 + l15) * LDSTRIDE + l4 * 8);
        }
#pragma unroll
        for (int i = 0; i < 4; i++)
#pragma unroll
            for (int j = 0; j < 4; j++)
                acc[i][j] = __builtin_amdgcn_mfma_f32_16x16x32_bf16(af[i], bfr[j], acc[i][j], 0, 0, 0);
    }

    __bf16* outp = scoresb + ((size_t)b * 256 + nt * 128) * 4096 + (size_t)mt * 128;
#pragma unroll
    for (int i = 0; i < 4; i++)
#pragma unroll
        for (int j = 0; j < 4; j++)
#pragma unroll
            for (int r = 0; r < 4; r++) {
                int n = wn0 + i * 16 + l4 * 4 + r;
                int m = wm0 + j * 16 + l15;
                outp[(size_t)n * 4096 + m] = (__bf16)acc[i][j][r];
            }
}

// ---------------- K3: top-8 (b128 coalesced) -> exact fp32 rescore -> top-4 ----------------
__global__ __launch_bounds__(256) void topk_rescore_kernel(const __bf16* __restrict__ scoresb,
                                                           const float* __restrict__ teacher,
                                                           const int* __restrict__ ref_perm,
                                                           const float* __restrict__ invnorm,
                                                           int* __restrict__ topk) {
    int row = blockIdx.x;  // b*256+n
    int b = row >> 8, n = row & 255;
    int t = threadIdx.x;
    int lane = t & 63, wave = t >> 6;

    __shared__ float refr[1024];
    __shared__ float cval[32];
    __shared__ int cidx[32];
    __shared__ int cand_i[8];
    __shared__ float exact_v[8];

    const float* Tb = teacher + (size_t)b * 8 * 1024 * 1024;
    int rp = ref_perm[n];
    ((float4*)refr)[t] = ((const float4*)(Tb + (size_t)rp * 1024))[t];

    // coalesced score load: thread t owns m in [16t, 16t+16)
    const __bf16* srow = scoresb + (size_t)row * 4096;
    __bf16 xs[16];
    *(uint4*)xs = ((const uint4*)srow)[2 * t];
    *(uint4*)(xs + 8) = ((const uint4*)srow)[2 * t + 1];

    float v[8]; int ix[8];
#pragma unroll
    for (int i = 0; i < 8; i++) { v[i] = -1e38f; ix[i] = -1; }
#pragma unroll
    for (int jj = 0; jj < 16; jj++) {
        float xv = (float)xs[jj]; int xm = t * 16 + jj;
        if (xv > v[7]) {
            v[7] = xv; ix[7] = xm;
#pragma unroll
            for (int i = 7; i > 0; i--)
                if (v[i] > v[i - 1]) {
                    float tv = v[i]; v[i] = v[i - 1]; v[i - 1] = tv;
                    int ti = ix[i]; ix[i] = ix[i - 1]; ix[i - 1] = ti;
                }
        }
    }
    // wave-level top-8: butterfly argmax on heads + static pop
    for (int r = 0; r < 8; r++) {
        float bv = v[0]; int bi = ix[0];
        for (int o = 32; o > 0; o >>= 1) {
            float ov = __shfl_xor(bv, o); int oi = __shfl_xor(bi, o);
            if (ov > bv || (ov == bv && oi > bi)) { bv = ov; bi = oi; }
        }
        if (lane == 0) { cval[wave * 8 + r] = bv; cidx[wave * 8 + r] = bi; }
        if (bi == ix[0]) {
            v[0] = v[1]; ix[0] = ix[1];
            v[1] = v[2]; ix[1] = ix[2];
            v[2] = v[3]; ix[2] = ix[3];
            v[3] = v[4]; ix[3] = ix[4];
            v[4] = v[5]; ix[4] = ix[5];
            v[5] = v[6]; ix[5] = ix[6];
            v[6] = v[7]; ix[6] = ix[7];
            v[7] = -1e38f; ix[7] = -1;
        }
    }
    __syncthreads();
    if (wave == 0) {   // block merge: 32 candidates -> top-8
        float mv = (lane < 32) ? cval[lane] : -1e38f;
        int mi = (lane < 32) ? cidx[lane] : -1;
        for (int r = 0; r < 8; r++) {
            float bv = mv; int bi = mi;
            for (int o = 32; o > 0; o >>= 1) {
                float ov = __shfl_xor(bv, o); int oi = __shfl_xor(bi, o);
                if (ov > bv || (ov == bv && oi > bi)) { bv = ov; bi = oi; }
            }
            if (lane == 0) cand_i[r] = bi;
            if (bi == mi) mv = -1e38f;
        }
    }
    __syncthreads();
    // exact fp32 rescore straight from global (rows are L2/L3 hot)
    for (int c = wave; c < 8; c += 4) {
        int m = cand_i[c];
        int frame = 1 + 2 * (m >> 10), p = m & 1023;
        const float* ext = Tb + ((size_t)frame * 1024 + p) * 1024;
        float s = 0.f;
#pragma unroll
        for (int jj = 0; jj < 16; jj++) {
            int d = lane + 64 * jj;
            s = fmaf(refr[d], ext[d], s);
        }
        for (int o = 32; o > 0; o >>= 1) s += __shfl_xor(s, o);
        if (lane == 0) exact_v[c] = s * invnorm[b * 4096 + m];
    }
    __syncthreads();
    if (t == 0) {
        unsigned used = 0;
        for (int r = 0; r < 4; r++) {
            float bv = -1e38f; int bc = 0;
            for (int c = 0; c < 8; c++)
                if (!(used & (1u << c)) && exact_v[c] > bv) { bv = exact_v[c]; bc = c; }
            used |= 1u << bc;
            topk[row * 4 + r] = cand_i[bc];
        }
    }
}

// ---------------- K4: fused KL branches (monolithic, d2 computed once weight 3) ----------------
__global__ __launch_bounds__(256) void kl_kernel(const float* __restrict__ teacher,
                                                 const float* __restrict__ student,
                                                 const int* __restrict__ ref_perm,
                                                 const int* __restrict__ shared_perm,
                                                 const int* __restrict__ topk,
                                                 float* __restrict__ acc) {
    int row = blockIdx.x;        // b*256 + n
    int b = row >> 8;
    int n = row & 255;
    int t = threadIdx.x;
    int lane = t & 63, wave = t >> 6;

    __shared__ float rt[1024], rs[1024], st[1024], ss[1024];
    __shared__ float sh[4][1024];
    __shared__ float res3[3];
    if (t < 3) res3[t] = 0.f;

    const float* Tb = teacher + (size_t)b * 8 * 1024 * 1024;
    const float* Sb = student + (size_t)b * 4 * 1024 * 1024;

    int rp = ref_perm[n];
    ((float4*)rt)[t] = ((const float4*)(Tb + (size_t)rp * 1024))[t];
    ((float4*)rs)[t] = ((const float4*)(Sb + (size_t)rp * 1024))[t];
#pragma unroll
    for (int k = 0; k < 4; k++) {
        int idx = topk[row * 4 + k];
        int frame = 1 + 2 * (idx >> 10), p = idx & 1023;
        ((float4*)sh[k])[t] = ((const float4*)(Tb + ((size_t)frame * 1024 + p) * 1024))[t];
    }
    int sp = shared_perm[n];

    for (int ti = 0; ti < 3; ti++) {
        int t_idx = 2 * ti + 2;
        int s_idx = ti + 1;
        __syncthreads();   // prev iteration's st/ss reads done; also covers initial loads
        ((float4*)st)[t] = ((const float4*)(Tb + ((size_t)t_idx * 1024 + sp) * 1024))[t];
        ((float4*)ss)[t] = ((const float4*)(Sb + ((size_t)s_idx * 1024 + sp) * 1024))[t];
        __syncthreads();

        // ti==0: rows 0..8 (d2 rows 1..4 weighted x3); ti==1,2: rows {0,5,6,7,8} (d2 invariant)
        int nrows = (ti == 0) ? 9 : 5;
        for (int idx = wave; idx < nrows; idx += 4) {
            int r = (ti == 0) ? idx : (idx == 0 ? 0 : idx + 4);
            const float *At, *Bt, *Asx, *Bsx;
            int branch;
            float w = 1.f;
            if (r == 0)      { At = rt; Bt = st;        Asx = rs; Bsx = ss;        branch = 0; }
            else if (r < 5)  { At = rt; Bt = sh[r - 1]; Asx = rs; Bsx = sh[r - 1]; branch = 1; w = 3.f; }
            else             { At = st; Bt = sh[r - 5]; Asx = ss; Bsx = sh[r - 5]; branch = 2; }

            float dt[16], ds[16];
            float mt = -1e38f, ms = -1e38f;
#pragma unroll
            for (int j = 0; j < 16; j++) {
                int d = lane + 64 * j;
                dt[j] = At[d] - Bt[d];
                ds[j] = Asx[d] - Bsx[d];
                mt = fmaxf(mt, dt[j]);
                ms = fmaxf(ms, ds[j]);
            }
            for (int o = 32; o > 0; o >>= 1) {
                mt = fmaxf(mt, __shfl_xor(mt, o));
                ms = fmaxf(ms, __shfl_xor(ms, o));
            }
            float Zt = 0.f, Zs = 0.f, Tn = 0.f;
#pragma unroll
            for (int j = 0; j < 16; j++) {
                float et = __expf(dt[j] - mt);
                Zt += et;
                Zs += __expf(ds[j] - ms);
                Tn += et * (dt[j] - ds[j]);
            }
            for (int o = 32; o > 0; o >>= 1) {
                Zt += __shfl_xor(Zt, o);
                Zs += __shfl_xor(Zs, o);
                Tn += __shfl_xor(Tn, o);
            }
            if (lane == 0) {
                float kl = Tn / Zt - mt - __logf(Zt) + ms + __logf(Zs);
                float ax = fabsf(kl);
                float h = ax < 0.5f ? ax * ax : ax - 0.25f;
                atomicAdd(&res3[branch], h * w);
            }
        }
    }
    __syncthreads();
    if (t < 3) atomicAdd(&acc[t], res3[t]);
}

// ---------------- K5: finalize ----------------
__global__ void finalize_kernel(const float* __restrict__ acc, float* __restrict__ out) {
    out[0] = acc[0] / 3072.f + acc[1] / 12288.f + acc[2] / 12288.f;
}

extern "C" void kernel_launch(void* const* d_in, const int* in_sizes, int n_in,
                              void* d_out, int out_size, void* d_ws, size_t ws_size,
                              hipStream_t stream) {
    const float* teacher = (const float*)d_in[0];
    const float* student = (const float*)d_in[1];
    const int* ref_perm = (const int*)d_in[2];
    const int* shared_perm = (const int*)d_in[3];
    float* out = (float*)d_out;

    char* ws = (char*)d_ws;
    float* acc     = (float*)ws;                         // 64 B
    float* invnorm = (float*)(ws + 64);                  // 16384 floats
    int*   topk    = (int*)(ws + 64 + 65536);            // 4096 ints
    __bf16* Abf    = (__bf16*)(ws + 64 + 65536 + 16384); // 4*256*1024
    __bf16* Bbf    = Abf + (size_t)4 * 256 * 1024;       // 4*4096*1024
    __bf16* scoresb = Bbf + (size_t)4 * 4096 * 1024;     // 4*256*4096

    convert_kernel<<<BATCH * 4352, 256, 0, stream>>>(teacher, ref_perm, Abf, Bbf, invnorm, acc);
    mfma_gemm_kernel<<<dim3(32, 2, 4), 256, 0, stream>>>(Abf, Bbf, scoresb);
    topk_rescore_kernel<<<1024, 256, 0, stream>>>(scoresb, teacher, ref_perm, invnorm, topk);
    kl_kernel<<<1024, 256, 0, stream>>>(teacher, student, ref_perm, shared_perm, topk, acc);
    finalize_kernel<<<1, 1, 0, stream>>>(acc, out);
}